// Round 11
// baseline (200.673 us; speedup 1.0000x reference)
//
#include <hip/hip_runtime.h>

typedef unsigned int u32;
typedef unsigned short u16;
typedef __attribute__((ext_vector_type(8))) short bf16x8;   // 8 bf16 in 4 VGPRs
typedef __attribute__((ext_vector_type(4))) float f32x4;

#define NPTS 4096
#define DIM  64
#define NB   32          // 4096/128
#define TS   128
#define NBLK 528         // NB*(NB+1)/2 upper-tri blocks
#define WLO16 0x4140u    // window low: float bits 0x41400000 = 12.0
#define NWBIN 832        // t16 in [0x4140, 0x4480) -> D in [12, 1024)

// map linear upper-tri block id -> (by,bx), bx>=by
__device__ __forceinline__ void bmap(int b, int& by, int& bx){
  by = 0;
  while (b >= NB - by){ b -= NB - by; by++; }
  bx = by + b;
}

// fp32 -> bf16 bits, round-nearest-even
__device__ __forceinline__ u16 f2bf(float x){
  u32 u = __float_as_uint(x);
  return (u16)((u + 0x7fffu + ((u>>16)&1u)) >> 16);
}

// ---------- pre-pass: X,Y -> bf16 rows + fp32 squared norms ----------
__global__ __launch_bounds__(256) void convert_k(const float* __restrict__ X, const float* __restrict__ Y,
                                                 u16* __restrict__ Xbf, float* __restrict__ Gall){
  int t = blockIdx.x*256 + threadIdx.x;     // 8192 threads, one row each
  int z = t >> 12, row = t & 4095;
  const float* src = (z ? Y : X) + (size_t)row*DIM;
  u16* dst = Xbf + (size_t)t*DIM;
  float g = 0.f;
#pragma unroll
  for (int k=0;k<DIM;k+=4){
    float4 f = *(const float4*)(src+k);
    g = fmaf(f.x,f.x,g); g = fmaf(f.y,f.y,g); g = fmaf(f.z,f.z,g); g = fmaf(f.w,f.w,g);
    ushort4 h; h.x=f2bf(f.x); h.y=f2bf(f.y); h.z=f2bf(f.z); h.w=f2bf(f.w);
    *(ushort4*)(dst+k) = h;
  }
  Gall[t] = g;
}

// ---------- MFMA D sub-tile: 16 rows x 128 cols (validated rounds 7-10, absmax 0.0) ----------
__device__ __forceinline__ void dtile1(const bf16x8* __restrict__ Xb, const float* __restrict__ Gz,
                                       int rowA, int j0, int q, int nl, float (&Dv)[8][4])
{
  f32x4 acc[8];
#pragma unroll
  for (int b=0;b<8;b++) acc[b] = (f32x4)0.0f;
#pragma unroll
  for (int kh=0; kh<2; kh++){
    bf16x8 afr = Xb[(size_t)rowA*8 + kh*4 + q];
#pragma unroll
    for (int tb=0; tb<8; tb++){
      bf16x8 bfr = Xb[(size_t)(j0 + tb*16 + nl)*8 + kh*4 + q];
      acc[tb] = __builtin_amdgcn_mfma_f32_16x16x32_bf16(afr, bfr, acc[tb], 0,0,0);
    }
  }
  float ga = Gz[rowA];
  float gAm[4];
#pragma unroll
  for (int r=0;r<4;r++) gAm[r] = __shfl(ga, q*4+r, 64);
#pragma unroll
  for (int tb=0;tb<8;tb++){
    float gb = Gz[j0 + tb*16 + nl];
#pragma unroll
    for (int r=0;r<4;r++)
      Dv[tb][r] = (gAm[r] + gb) - 2.0f*acc[tb][r];
  }
}

// ---------- pass 1: histogram only (half-tile blocks: 64 rows each) ----------
__global__ __launch_bounds__(256,2) void hist_k(const u16* __restrict__ Xbf, const float* __restrict__ Gall,
                                                u32* __restrict__ hist16){
  __shared__ u32 lh[NWBIN+2];
  int z = blockIdx.y, tid = threadIdx.x;
  int bid = blockIdx.x >> 1, half = blockIdx.x & 1;
  int by,bx; bmap(bid,by,bx);
  bool isdiag = (by==bx);
  int i0=by*TS, j0=bx*TS;
  for (int t=tid;t<NWBIN+2;t+=256) lh[t]=0;
  __syncthreads();
  int w=tid>>6, lane=tid&63, q=lane>>4, nl=lane&15;
  const bf16x8* Xb = (const bf16x8*)Xbf + (size_t)z*NPTS*8;
  const float* Gz = Gall + z*NPTS;
  int rt = half*4 + w;
  float Dv[8][4];
  dtile1(Xb, Gz, i0 + rt*16 + nl, j0, q, nl, Dv);
#pragma unroll
  for (int tb=0;tb<8;tb++){
    int jl = tb*16+nl;
#pragma unroll
    for (int r=0;r<4;r++){
      int il = rt*16+q*4+r;
      if (!isdiag || jl > il){
        u32 t16 = __float_as_uint(Dv[tb][r]) >> 16;
        u32 bin = (t16 < WLO16) ? 0u
                : (t16 >= WLO16+NWBIN) ? (u32)(NWBIN+1)
                : (t16 - WLO16 + 1u);
        atomicAdd(&lh[bin], 1u);
      }
    }
  }
  __syncthreads();
  for (int t=tid;t<NWBIN+2;t+=256){ u32 c=lh[t]; if(c) atomicAdd(&hist16[z*(NWBIN+2)+t], c); }
}

// ---------- parallel select: 4 bins/thread, shuffle prefix, interpolate; zero rowK/rowL ----------
__global__ __launch_bounds__(256) void scan16i(const u32* __restrict__ hist16,
                                               float* __restrict__ scal,
                                               double* __restrict__ rowK, double* __restrict__ rowL,
                                               u32 k1, u32 k2){
  int z = blockIdx.x;
  int tid = threadIdx.x;
  double* rz = z ? rowL : rowK;
  for (int i=tid;i<NPTS;i+=256) rz[i]=0.0;
  __shared__ u32 v[1024];
  __shared__ u32 wsum[4];
  __shared__ double svals[2];
  for (int t=tid;t<1024;t+=256) v[t] = (t<NWBIN+2) ? hist16[z*(NWBIN+2)+t] : 0u;
  __syncthreads();
  uint4 cv = ((const uint4*)v)[tid];
  u32 c4[4] = {cv.x, cv.y, cv.z, cv.w};
  u32 s = c4[0]+c4[1]+c4[2]+c4[3];
  int lane = tid & 63, wv = tid >> 6;
  u32 pre = s;
#pragma unroll
  for (int off=1; off<64; off<<=1){
    u32 t2 = __shfl_up(pre, off, 64);
    if (lane >= off) pre += t2;
  }
  if (lane==63) wsum[wv] = pre;
  __syncthreads();
  u32 base = 0;
  for (int k=0;k<wv;k++) base += wsum[k];
  u32 incl = base + pre, excl = incl - s;
  u32 ks[2] = {k1,k2};
#pragma unroll
  for (int w2=0; w2<2; w2++){
    if (ks[w2] >= excl && ks[w2] < incl){
      u32 acc = excl;
#pragma unroll
      for (int j=0;j<4;j++){
        if (ks[w2] < acc + c4[j]){
          int b = tid*4 + j;
          double lo, hi;
          if (b==0){ lo=12.0; hi=12.0; }
          else if (b>=NWBIN+1){ lo=1024.0; hi=1024.0; }
          else {
            u32 t16 = WLO16 + (u32)b - 1u;
            lo = (double)__uint_as_float(t16<<16);
            hi = (double)__uint_as_float((t16+1u)<<16);
          }
          double frac = ((double)(ks[w2]-acc) + 0.5)/(double)c4[j];
          svals[w2] = lo + (hi-lo)*frac;
          break;
        }
        acc += c4[j];
      }
    }
  }
  __syncthreads();
  if (tid==0){
    float med = (float)(0.5*(svals[0]+svals[1]));
    float wd = sqrtf(0.5f*med);
    scal[z] = 2.0f*wd*wd;
  }
}

// ---------- pass 2: recompute D, exp, row/col sums (half-tile blocks) ----------
__global__ __launch_bounds__(256,2) void rowsum_k(const u16* __restrict__ Xbf, const float* __restrict__ Gall,
                                                  const float* __restrict__ scal,
                                                  double* __restrict__ rowK, double* __restrict__ rowL){
  int z = blockIdx.y, tid = threadIdx.x;
  int bid = blockIdx.x >> 1, half = blockIdx.x & 1;
  int by,bx; bmap(bid,by,bx);
  bool isdiag = (by==bx);
  int i0=by*TS, j0=bx*TS;
  int w=tid>>6, lane=tid&63, q=lane>>4, nl=lane&15;
  const bf16x8* Xb = (const bf16x8*)Xbf + (size_t)z*NPTS*8;
  const float* Gz = Gall + z*NPTS;
  double* rowS = z ? rowL : rowK;
  float negi = -1.0f/scal[z];
  int rt = half*4 + w;
  float Dv[8][4];
  dtile1(Xb, Gz, i0 + rt*16 + nl, j0, q, nl, Dv);
  double cs[8];
  double rs[4] = {0,0,0,0};
#pragma unroll
  for (int tb=0;tb<8;tb++){
    int jl = tb*16+nl;
    double c = 0;
#pragma unroll
    for (int r=0;r<4;r++){
      int il = rt*16+q*4+r;
      float d = Dv[tb][r];
      if (isdiag && il==jl) d = 0.f;      // exact K_ii = 1
      float e = expf(d*negi);
      rs[r] += e; c += e;
    }
    cs[tb] = c;
  }
#pragma unroll
  for (int r=0;r<4;r++){
    double v2 = rs[r];
    v2 += __shfl_xor(v2,1,64); v2 += __shfl_xor(v2,2,64);
    v2 += __shfl_xor(v2,4,64); v2 += __shfl_xor(v2,8,64);
    if (nl==0) atomicAdd(&rowS[i0 + rt*16 + q*4 + r], v2);
  }
  if (!isdiag){
#pragma unroll
    for (int tb=0;tb<8;tb++){
      double v2 = cs[tb];
      v2 += __shfl_xor(v2,16,64); v2 += __shfl_xor(v2,32,64);
      if (q==0) atomicAdd(&rowS[j0 + tb*16 + nl], v2);
    }
  }
}

// ---------- totals of rowK/rowL ----------
__global__ __launch_bounds__(256) void reduce_rows(const double* __restrict__ rowK,
                                                   const double* __restrict__ rowL,
                                                   double* __restrict__ sums){
  __shared__ double sd[256];
  int t=threadIdx.x;
  double s=0; for(int i=t;i<NPTS;i+=256) s+=rowK[i];
  sd[t]=s; __syncthreads();
  for(int off=128;off>0;off>>=1){ if(t<off) sd[t]+=sd[t+off]; __syncthreads(); }
  if(t==0) sums[0]=sd[0];
  __syncthreads();
  s=0; for(int i=t;i<NPTS;i+=256) s+=rowL[i];
  sd[t]=s; __syncthreads();
  for(int off=128;off>0;off>>=1){ if(t<off) sd[t]+=sd[t+off]; __syncthreads(); }
  if(t==0) sums[1]=sd[0];
}

// ---------- pass 3: per-column-group K,L recompute + centered products (half-tile blocks) ----------
__global__ __launch_bounds__(256,2) void final_k(const u16* __restrict__ Xbf, const float* __restrict__ Gall,
                                                 const float* __restrict__ scal,
                                                 const double* __restrict__ rowK,
                                                 const double* __restrict__ rowL,
                                                 const double* __restrict__ sums,
                                                 double* __restrict__ partials){
  int tid = threadIdx.x;
  int b = blockIdx.x >> 1, half = blockIdx.x & 1;
  int by,bx; bmap(b,by,bx);
  bool isdiag = (by==bx);
  int i0=by*TS, j0=bx*TS;
  int w=tid>>6, lane=tid&63, q=lane>>4, nl=lane&15;
  const bf16x8* Xb = (const bf16x8*)Xbf;
  const bf16x8* Yb = Xb + (size_t)NPTS*8;
  const float* Gx = Gall;
  const float* Gy = Gall + NPTS;
  const double inv_n = 1.0/(double)NPTS;
  double tmK = sums[0]*(inv_n*inv_n), tmL = sums[1]*(inv_n*inv_n);
  float negx = -1.0f/scal[0], negy = -1.0f/scal[1];
  double wgt = isdiag ? 1.0 : 2.0;
  double S1=0, S2=0, trV=0;
  int rt = half*4 + w;
  int rowA = i0 + rt*16 + nl;
  bf16x8 axf0 = Xb[(size_t)rowA*8 + q];
  bf16x8 axf1 = Xb[(size_t)rowA*8 + 4 + q];
  bf16x8 ayf0 = Yb[(size_t)rowA*8 + q];
  bf16x8 ayf1 = Yb[(size_t)rowA*8 + 4 + q];
  float gaX = Gx[rowA], gaY = Gy[rowA];
  float gXm[4], gYm[4];
#pragma unroll
  for (int r=0;r<4;r++){ gXm[r] = __shfl(gaX, q*4+r, 64); gYm[r] = __shfl(gaY, q*4+r, 64); }
  double rmKi[4], rmLi[4];
#pragma unroll
  for (int r=0;r<4;r++){
    int i = i0 + rt*16 + q*4 + r;
    rmKi[r] = rowK[i]*inv_n; rmLi[r] = rowL[i]*inv_n;
  }
#pragma unroll
  for (int tb=0;tb<8;tb++){
    int jrow = j0 + tb*16 + nl;
    f32x4 accX = (f32x4)0.0f, accY = (f32x4)0.0f;
    accX = __builtin_amdgcn_mfma_f32_16x16x32_bf16(axf0, Xb[(size_t)jrow*8 + q],     accX, 0,0,0);
    accX = __builtin_amdgcn_mfma_f32_16x16x32_bf16(axf1, Xb[(size_t)jrow*8 + 4 + q], accX, 0,0,0);
    accY = __builtin_amdgcn_mfma_f32_16x16x32_bf16(ayf0, Yb[(size_t)jrow*8 + q],     accY, 0,0,0);
    accY = __builtin_amdgcn_mfma_f32_16x16x32_bf16(ayf1, Yb[(size_t)jrow*8 + 4 + q], accY, 0,0,0);
    float gbX = Gx[jrow], gbY = Gy[jrow];
    double cmK = rowK[jrow]*inv_n - tmK;
    double cmL = rowL[jrow]*inv_n - tmL;
    int jl = tb*16 + nl;
#pragma unroll
    for (int r=0;r<4;r++){
      int il = rt*16 + q*4 + r;
      float dx = (gXm[r] + gbX) - 2.0f*accX[r];
      float dy = (gYm[r] + gbY) - 2.0f*accY[r];
      bool dg = isdiag && il==jl;
      if (dg){ dx = 0.f; dy = 0.f; }
      float kx = expf(dx*negx);
      float lv = expf(dy*negy);
      double kc = ((double)kx - rmKi[r]) - cmK;
      double lc = ((double)lv - rmLi[r]) - cmL;
      double prod = kc*lc;
      S1 += wgt*prod;
      double vv = (prod*prod)*(1.0/36.0);
      S2 += wgt*vv;
      if (dg) trV += vv;
    }
  }
  __shared__ double red[4][3];
  double vals[3]={S1,S2,trV};
  int wv = tid >> 6;
#pragma unroll
  for (int v=0;v<3;v++){
    double x = vals[v];
#pragma unroll
    for (int s2=1;s2<64;s2<<=1) x += __shfl_xor(x, s2, 64);
    if (lane==0) red[wv][v]=x;
  }
  __syncthreads();
  if (tid < 3)
    partials[(size_t)blockIdx.x*4 + tid] = red[0][tid]+red[1][tid]+red[2][tid]+red[3][tid];
}

// ---------- wave-parallel regularized lower incomplete gamma P(a,x) ----------
__device__ double gammainc_wave(double a, double x, double lga, int lane){
  double C = 1.0/a;
  double psum = 0.0;
  for (int b=0;b<8192;b++){
    double k = (double)(b*64 + lane + 1);
    double rr = x/(a+k);
    double pp = rr;
#pragma unroll
    for (int s=1;s<64;s<<=1){
      double t = __shfl_up(pp, s, 64);
      if (lane >= s) pp *= t;
    }
    double c = C*pp;
    psum += c;
    double clast = __shfl(c, 63, 64);
    double rlast = __shfl(rr, 63, 64);
    C = clast;
    if (rlast < 1.0 && clast*rlast/(1.0-rlast) < 1e-17) break;
  }
#pragma unroll
  for (int s=1;s<64;s<<=1) psum += __shfl_xor(psum, s, 64);
  double total = 1.0/a + psum;
  return exp(-x + a*log(x) - lga) * total;
}

// ---------- reduce partials + Newton ----------
__global__ __launch_bounds__(256) void finalize_k(const double* __restrict__ partials,
                                                  const double* __restrict__ sums,
                                                  float* __restrict__ out)
{
  __shared__ double red[3][4];
  __shared__ double tot[4];
  int tid = threadIdx.x;
  double v0=0,v1=0,v2=0;
  for (int i=tid; i<2*NBLK; i+=256){
    const double* p = partials + (size_t)i*4;
    v0+=p[0]; v1+=p[1]; v2+=p[2];
  }
  double vals[3]={v0,v1,v2};
  int lane = tid & 63, wv = tid >> 6;
#pragma unroll
  for (int v=0;v<3;v++){
    double x = vals[v];
#pragma unroll
    for (int s2=1;s2<64;s2<<=1) x += __shfl_xor(x, s2, 64);
    if (lane==0) red[v][wv]=x;
  }
  __syncthreads();
  if (tid==0){
#pragma unroll
    for (int v=0;v<3;v++) tot[v] = red[v][0]+red[v][1]+red[v][2]+red[v][3];
  }
  __syncthreads();
  if (tid >= 64) return;

  const double n = (double)NPTS;
  double totK=sums[0], totL=sums[1];
  double S1=tot[0], S2=tot[1], trV=tot[2];
  double testStat = S1/n;
  double varHSIC = (S2 - trV)/n/(n-1.0);
  varHSIC = varHSIC*72.0*(n-4.0)*(n-5.0)/n/(n-1.0)/(n-2.0)/(n-3.0);
  double muX = (totK-n)/n/(n-1.0);   // trace(K) = n exactly (diag forced to 1)
  double muY = (totL-n)/n/(n-1.0);
  double mHSIC = (1.0 + muX*muY - muX - muY)/n;
  double al = mHSIC*mHSIC/varHSIC;
  double bet = varHSIC*n/mHSIC;
  double p = (double)((float)(1.0-0.8));
  double lga = lgamma(al);
  double lo = 0.0, hi = al + 10.0*sqrt(al) + 100.0;
  const double zp = -0.8416212335729142957;  // Phi^-1(0.2)
  double t = 1.0 - 1.0/(9.0*al) + zp/(3.0*sqrt(al));
  double x = al*t*t*t;
  if (!(x > 0.0) || !(x < hi)) x = 0.5*hi;
  for (int it=0; it<2; ++it){
    double P = gammainc_wave(al, x, lga, lane);
    double diff = P - p;
    if (diff < 0.0) lo = x; else hi = x;
    if (fabs(diff) < 1e-12) break;
    double pdf = exp(-x + (al-1.0)*log(x) - lga);
    double nx = x - diff/pdf;
    if (!(nx > lo) || !(nx < hi)) nx = 0.5*(lo+hi);
    x = nx;
  }
  if (lane==0){
    out[0]=(float)testStat;
    out[1]=(float)(bet*x);
  }
}

// ---------- host ----------
extern "C" void kernel_launch(void* const* d_in, const int* in_sizes, int n_in,
                              void* d_out, int out_size, void* d_ws, size_t ws_size,
                              hipStream_t stream) {
  const float* X = (const float*)d_in[0];
  const float* Y = (const float*)d_in[1];
  float* out = (float*)d_out;
  char* ws = (char*)d_ws;

  double* sums     = (double*)ws;                    // 2 doubles @0
  float*  scal     = (float*)(ws + 128);             // 2 floats
  u32*    hist16   = (u32*)(ws + 256);               // [2][834] u32 = 6672 B
  double* rowK     = (double*)(ws + 8192);           // 32 KB
  double* rowL     = (double*)(ws + 40960);          // 32 KB
  float*  Gall     = (float*)(ws + 73728);           // 2*4096 fp32 = 32 KB
  double* partials = (double*)(ws + 106496);         // 1056*4 doubles = 33792 B
  u16*    Xbf      = (u16*)(ws + 147456);            // 2*4096*64 bf16 = 1 MB
  size_t need = 147456 + (size_t)2*NPTS*DIM*2;       // ~1.2 MB

  if (ws_size < need) return;

  hipMemsetAsync(ws + 256, 0, 6672, stream);         // hist16 only

  const u32 K1 = 4193279u, K2 = 4193280u;  // m = 4096*4095/2; median = avg of ranks m/2-1, m/2

  convert_k<<<32,256,0,stream>>>(X, Y, Xbf, Gall);
  hist_k<<<dim3(2*NBLK,2),256,0,stream>>>(Xbf, Gall, hist16);
  scan16i<<<2,256,0,stream>>>(hist16, scal, rowK, rowL, K1, K2);
  rowsum_k<<<dim3(2*NBLK,2),256,0,stream>>>(Xbf, Gall, scal, rowK, rowL);
  reduce_rows<<<1,256,0,stream>>>(rowK, rowL, sums);
  final_k<<<2*NBLK,256,0,stream>>>(Xbf, Gall, scal, rowK, rowL, sums, partials);
  finalize_k<<<1,256,0,stream>>>(partials, sums, out);
}